// Round 5
// baseline (740.858 us; speedup 1.0000x reference)
//
#include <hip/hip_runtime.h>

#define PAD   4
#define DD    9
#define ND    81
#define CCH   256
#define HH_   128
#define WW_   224
#define TH    8
#define TW    32
#define NTILES 448               // 7 wtiles * 16 htiles * 4 batch
#define PLANE  (HH_*WW_)         // 28672

#define CB    4                  // channels per stage
#define NSTG  (CCH/CB)           // 64 stages
// LDS layout (floats)
#define S_CH   640               // 16 rows * 40 floats (second halo tile)
#define S_BUF  (CB*S_CH)         // 2560 floats per parity
#define F_CH   256               // 8 rows * 32 floats (first tile)
#define F_BUF  (CB*F_CH)         // 1024 floats per parity
#define F_BASE (2*S_BUF)         // 5120
#define LDSF   (2*S_BUF + 2*F_BUF)  // 7168 floats = 28 KB

__global__ __launch_bounds__(576, 5)   // cap VGPR ~96 -> 2 blocks/CU resident
void corr_kernel(const float* __restrict__ first,
                 const float* __restrict__ second,
                 float* __restrict__ out)
{
    __shared__ float lds[LDSF];

    const int bx   = blockIdx.x;                 // 0..447
    // XCD-chunked bijective swizzle (448 % 8 == 0): each XCD gets a
    // contiguous vertical (b,ht) strip -> halo-row overlap stays in its L2.
    const int tile = (bx & 7) * 56 + (bx >> 3);
    const int wt   = tile % 7;
    const int ht   = (tile / 7) % 16;
    const int b    = tile / 112;
    const int w0   = wt * TW, h0 = ht * TH;

    const int tid  = threadIdx.x;                // 0..575
    const int dy   = tid >> 6;                   // wave id = dy (0..8)
    const int lane = tid & 63;
    const int wq   = lane & 7;                   // column quad
    const int hh   = lane >> 3;                  // row within tile

    // ---------- staging descriptors (2 slots/thread, loop-invariant) ----------
    const float* gp[2];  int lo[2];  int po[2];  bool av[2];
    {
        float4 z; z.x = 0.f; z.y = 0.f; z.z = 0.f; z.w = 0.f;
        #pragma unroll
        for (int it = 0; it < 2; ++it) {
            const int t = tid + it * 576;
            const bool act = (t < 896);
            const bool isS = (t < 640);
            bool val = false;
            const float* p = first;
            int off = 0;
            if (isS) {                           // second halo tile: 4ch x 16r x 10q
                const int c_ = t / 160;
                const int r  = t - c_ * 160;
                const int sr = r / 10;
                const int j  = r - sr * 10;
                const int grow = h0 - PAD + sr;
                const int gcol = w0 - PAD + 4 * j;
                val = (grow >= 0) && (grow < HH_) && (gcol >= 0) && (gcol < WW_);
                p = second + ((size_t)b * CCH + c_) * PLANE
                           + (size_t)(val ? grow : 0) * WW_ + (val ? gcol : 0);
                off = c_ * S_CH + sr * 40 + j * 4;
                // permanently-OOB halo quads: zero both parities ONCE
                if (act && !val) {
                    *(float4*)&lds[off]         = z;
                    *(float4*)&lds[off + S_BUF] = z;
                }
                po[it] = S_BUF;
            } else {                             // first tile: 4ch x 8r x 8q (always valid)
                const int u  = t - 640;
                const int c_ = u >> 6;
                const int r  = u & 63;
                const int fr = r >> 3;
                const int fq = r & 7;
                val = act;
                p = first + ((size_t)b * CCH + c_) * PLANE
                          + (size_t)(h0 + fr) * WW_ + (w0 + 4 * fq);
                off = F_BASE + c_ * F_CH + fr * 32 + fq * 4;
                po[it] = F_BUF;
            }
            gp[it] = p;  lo[it] = off;  av[it] = act && val;
        }
    }

    // ---------- prologue: stage 0 into parity 0 ----------
    {
        float4 q0, q1;
        if (av[0]) { q0 = *(const float4*)gp[0]; gp[0] += (size_t)CB * PLANE; }
        if (av[1]) { q1 = *(const float4*)gp[1]; gp[1] += (size_t)CB * PLANE; }
        if (av[0]) *(float4*)&lds[lo[0]] = q0;
        if (av[1]) *(float4*)&lds[lo[1]] = q1;
    }
    __syncthreads();

    // ---------- per-wave read bases ----------
    const int sr_rd = hh + dy;                   // 0..15, S-tile row
    const float* sl0 = &lds[sr_rd * 40 + wq * 4];
    const float* fl0 = &lds[F_BASE + hh * 32 + wq * 4];

    float acc[DD][4];
    #pragma unroll
    for (int dx = 0; dx < DD; ++dx) { acc[dx][0]=0.f; acc[dx][1]=0.f; acc[dx][2]=0.f; acc[dx][3]=0.f; }

    // ---------- main loop: 64 stages, double-buffered ----------
    for (int s = 0; s < NSTG; ++s) {
        const int cur = s & 1, nxt = cur ^ 1;
        const bool has = (s + 1 < NSTG);

        // issue next-stage global loads EARLY (land during compute)
        float4 q0n, q1n;
        if (has && av[0]) { q0n = *(const float4*)gp[0]; gp[0] += (size_t)CB * PLANE; }
        if (has && av[1]) { q1n = *(const float4*)gp[1]; gp[1] += (size_t)CB * PLANE; }

        // compute CB channels from buffer `cur` (pure-LDS inner loop)
        const float* sl = sl0 + cur * S_BUF;
        const float* fl = fl0 + cur * F_BUF;
        #pragma unroll
        for (int cc = 0; cc < CB; ++cc) {
            float4 q0 = *(const float4*)(sl + cc * S_CH);        // s window quads
            float4 q1 = *(const float4*)(sl + cc * S_CH + 4);
            float4 q2 = *(const float4*)(sl + cc * S_CH + 8);
            float4 fq = *(const float4*)(fl + cc * F_CH);        // first quad

            const float sv[12] = { q0.x, q0.y, q0.z, q0.w,
                                   q1.x, q1.y, q1.z, q1.w,
                                   q2.x, q2.y, q2.z, q2.w };
            const float fv[4]  = { fq.x, fq.y, fq.z, fq.w };

            #pragma unroll
            for (int dx = 0; dx < DD; ++dx)
                #pragma unroll
                for (int px = 0; px < 4; ++px)
                    acc[dx][px] += fv[px] * sv[dx + px];
        }

        // write next stage LATE (vmcnt wait hidden under the FMAs above)
        if (has) {
            if (av[0]) *(float4*)&lds[lo[0] + nxt * po[0]] = q0n;
            if (av[1]) *(float4*)&lds[lo[1] + nxt * po[1]] = q1n;
        }
        __syncthreads();
    }

    // ---------- epilogue ----------
    const int h = h0 + hh, w = w0 + 4 * wq;
    const float inv = 1.0f / (float)CCH;
    #pragma unroll
    for (int dx = 0; dx < DD; ++dx) {
        const int d = dy * DD + dx;
        float4 o = make_float4(acc[dx][0]*inv, acc[dx][1]*inv,
                               acc[dx][2]*inv, acc[dx][3]*inv);
        *(float4*)&out[(((size_t)b * ND + d) * HH_ + h) * WW_ + w] = o;
    }
}

extern "C" void kernel_launch(void* const* d_in, const int* in_sizes, int n_in,
                              void* d_out, int out_size, void* d_ws, size_t ws_size,
                              hipStream_t stream) {
    const float* first  = (const float*)d_in[0];
    const float* second = (const float*)d_in[1];
    float* out = (float*)d_out;
    dim3 grid(NTILES);        // 448 blocks, 9 waves each (one dy per wave)
    dim3 block(9 * 64);
    corr_kernel<<<grid, block, 0, stream>>>(first, second, out);
}

// Round 6
// 437.510 us; speedup vs baseline: 1.6934x; 1.6934x over previous
//
#include <hip/hip_runtime.h>

#define PAD   4
#define DD    9
#define ND    81
#define CCH   256
#define HH_   128
#define WW_   224
#define TH    8
#define TW    32
#define NTILES 448               // 7 wtiles * 16 htiles * 4 batch
#define PLANE  (HH_*WW_)         // 28672

#define CB    4                  // channels per stage
#define NSTG  (CCH/CB)           // 64 stages
// LDS layout (floats)
#define SROW  40                 // second halo row: 16 rows * 40 floats
#define S_CH  (16*SROW)          // 640
#define S_BUF (CB*S_CH)          // 2560 per parity
#define FROW  40                 // first row padded 32->40: kills 8-way bank conflict
#define F_CH  (8*FROW)           // 320
#define F_BUF (CB*F_CH)          // 1280 per parity
#define F_BASE (2*S_BUF)         // 5120
#define LDSF   (2*S_BUF + 2*F_BUF)  // 7680 floats = 30 KB

// cross-lane neighbor fetch on the VALU pipe (no DS traffic).
// dst[i] = src[i-1]  (row_shr:1); cross-row/bound lanes are wq==0 -> overridden
__device__ __forceinline__ float dpp_from_left(float x) {
    int i = __builtin_bit_cast(int, x);
    i = __builtin_amdgcn_update_dpp(0, i, 0x111, 0xf, 0xf, true);
    return __builtin_bit_cast(float, i);
}
// dst[i] = src[i+1]  (row_shl:1); cross-row/bound lanes are wq==7 -> overridden
__device__ __forceinline__ float dpp_from_right(float x) {
    int i = __builtin_bit_cast(int, x);
    i = __builtin_amdgcn_update_dpp(0, i, 0x101, 0xf, 0xf, true);
    return __builtin_bit_cast(float, i);
}

__global__ __launch_bounds__(576)     // NO min-occupancy arg: round 5's (,5) forced
void corr_kernel(const float* __restrict__ first,   // VGPR=48 + 500MB scratch spill
                 const float* __restrict__ second,
                 float* __restrict__ out)
{
    __shared__ float lds[LDSF];

    const int bx   = blockIdx.x;                 // 0..447
    // XCD-chunked bijective swizzle (448 % 8 == 0)
    const int tile = (bx & 7) * 56 + (bx >> 3);
    const int wt   = tile % 7;
    const int ht   = (tile / 7) % 16;
    const int b    = tile / 112;
    const int w0   = wt * TW, h0 = ht * TH;

    const int tid  = threadIdx.x;                // 0..575
    const int dy   = tid >> 6;                   // wave id = dy (0..8)
    const int lane = tid & 63;
    const int wq   = lane & 7;                   // column quad
    const int hh   = lane >> 3;                  // row within tile
    const bool isL = (wq == 0), isR = (wq == 7);

    // ---------- staging descriptors (2 slots/thread, loop-invariant) ----------
    const float* gp[2];  int lo[2];  int po[2];  bool av[2];
    {
        float4 z; z.x = 0.f; z.y = 0.f; z.z = 0.f; z.w = 0.f;
        #pragma unroll
        for (int it = 0; it < 2; ++it) {
            const int t = tid + it * 576;
            const bool act = (t < 896);
            const bool isS = (t < 640);
            bool val = false;
            const float* p = first;
            int off = 0;
            if (isS) {                           // second halo tile: 4ch x 16r x 10q
                const int c_ = t / 160;
                const int r  = t - c_ * 160;
                const int sr = r / 10;
                const int j  = r - sr * 10;
                const int grow = h0 - PAD + sr;
                const int gcol = w0 - PAD + 4 * j;
                val = (grow >= 0) && (grow < HH_) && (gcol >= 0) && (gcol < WW_);
                p = second + ((size_t)b * CCH + c_) * PLANE
                           + (size_t)(val ? grow : 0) * WW_ + (val ? gcol : 0);
                off = c_ * S_CH + sr * SROW + j * 4;
                if (act && !val) {               // permanently-OOB quads: zero once
                    *(float4*)&lds[off]         = z;
                    *(float4*)&lds[off + S_BUF] = z;
                }
                po[it] = S_BUF;
            } else {                             // first tile: 4ch x 8r x 8q
                const int u  = t - 640;
                const int c_ = u >> 6;
                const int r  = u & 63;
                const int fr = r >> 3;
                const int fq = r & 7;
                val = act;
                p = first + ((size_t)b * CCH + c_) * PLANE
                          + (size_t)(h0 + fr) * WW_ + (w0 + 4 * fq);
                off = F_BASE + c_ * F_CH + fr * FROW + fq * 4;
                po[it] = F_BUF;
            }
            gp[it] = p;  lo[it] = off;  av[it] = act && val;
        }
    }

    // ---------- prologue: stage 0 into parity 0 ----------
    {
        float4 q0, q1;
        if (av[0]) { q0 = *(const float4*)gp[0]; gp[0] += (size_t)CB * PLANE; }
        if (av[1]) { q1 = *(const float4*)gp[1]; gp[1] += (size_t)CB * PLANE; }
        if (av[0]) *(float4*)&lds[lo[0]] = q0;
        if (av[1]) *(float4*)&lds[lo[1]] = q1;
    }
    __syncthreads();

    // ---------- per-wave read bases ----------
    const int sr_rd = hh + dy;                   // 0..15, S halo row
    const float* sl0 = &lds[sr_rd * SROW];       // col 0 of this lane's row
    const float* fl0 = &lds[F_BASE + hh * FROW + 4 * wq];

    float acc[DD][4];
    #pragma unroll
    for (int dx = 0; dx < DD; ++dx) { acc[dx][0]=0.f; acc[dx][1]=0.f; acc[dx][2]=0.f; acc[dx][3]=0.f; }

    // ---------- main loop: 64 stages, double-buffered ----------
    for (int s = 0; s < NSTG; ++s) {
        const int cur = s & 1, nxt = cur ^ 1;
        const bool has = (s + 1 < NSTG);

        // issue next-stage global loads EARLY (land during compute)
        float4 q0n, q1n;
        if (has && av[0]) { q0n = *(const float4*)gp[0]; gp[0] += (size_t)CB * PLANE; }
        if (has && av[1]) { q1n = *(const float4*)gp[1]; gp[1] += (size_t)CB * PLANE; }

        const float* sl = sl0 + cur * S_BUF;
        const float* fl = fl0 + cur * F_BUF;
        #pragma unroll
        for (int cc = 0; cc < CB; ++cc) {
            const float* srow_ = sl + cc * S_CH;
            // one mid-window b128 per lane; neighbors via DPP (VALU pipe)
            float4 m  = *(const float4*)(srow_ + 4 * wq + 4);
            float4 fq = *(const float4*)(fl + cc * F_CH);

            float4 a, c;
            a.x = dpp_from_left (m.x); a.y = dpp_from_left (m.y);
            a.z = dpp_from_left (m.z); a.w = dpp_from_left (m.w);
            c.x = dpp_from_right(m.x); c.y = dpp_from_right(m.y);
            c.z = dpp_from_right(m.z); c.w = dpp_from_right(m.w);
            if (isL | isR) {                     // 16-lane masked halo read
                float4 e = *(const float4*)(srow_ + (isR ? 36 : 0));
                if (isL) a = e; else c = e;
            }

            const float sv[12] = { a.x, a.y, a.z, a.w,
                                   m.x, m.y, m.z, m.w,
                                   c.x, c.y, c.z, c.w };
            const float fv[4]  = { fq.x, fq.y, fq.z, fq.w };

            #pragma unroll
            for (int dx = 0; dx < DD; ++dx)
                #pragma unroll
                for (int px = 0; px < 4; ++px)
                    acc[dx][px] += fv[px] * sv[dx + px];
        }

        // write next stage LATE (vmcnt wait hidden under the FMAs above)
        if (has) {
            if (av[0]) *(float4*)&lds[lo[0] + nxt * po[0]] = q0n;
            if (av[1]) *(float4*)&lds[lo[1] + nxt * po[1]] = q1n;
        }
        __syncthreads();
    }

    // ---------- epilogue ----------
    const int h = h0 + hh, w = w0 + 4 * wq;
    const float inv = 1.0f / (float)CCH;
    #pragma unroll
    for (int dx = 0; dx < DD; ++dx) {
        const int d = dy * DD + dx;
        float4 o = make_float4(acc[dx][0]*inv, acc[dx][1]*inv,
                               acc[dx][2]*inv, acc[dx][3]*inv);
        *(float4*)&out[(((size_t)b * ND + d) * HH_ + h) * WW_ + w] = o;
    }
}

extern "C" void kernel_launch(void* const* d_in, const int* in_sizes, int n_in,
                              void* d_out, int out_size, void* d_ws, size_t ws_size,
                              hipStream_t stream) {
    const float* first  = (const float*)d_in[0];
    const float* second = (const float*)d_in[1];
    float* out = (float*)d_out;
    dim3 grid(NTILES);        // 448 blocks, 9 waves each (one dy per wave)
    dim3 block(9 * 64);
    corr_kernel<<<grid, block, 0, stream>>>(first, second, out);
}